// Round 1
// baseline (619.726 us; speedup 1.0000x reference)
//
#include <hip/hip_runtime.h>
#include <hip/hip_bf16.h>

typedef __bf16 bf16x8 __attribute__((ext_vector_type(8)));
typedef float  f32x4  __attribute__((ext_vector_type(4)));

#define MFMA_BF16 __builtin_amdgcn_mfma_f32_16x16x32_bf16

static __device__ __forceinline__ bf16x8 pack8(float4 a, float4 b) {
    bf16x8 r;
    r[0] = (__bf16)a.x; r[1] = (__bf16)a.y; r[2] = (__bf16)a.z; r[3] = (__bf16)a.w;
    r[4] = (__bf16)b.x; r[5] = (__bf16)b.y; r[6] = (__bf16)b.z; r[7] = (__bf16)b.w;
    return r;
}

// ---------------------------------------------------------------------------
// Kernel 1: qkv = hs @ Wqkv^T + bqkv, then per-head L2 norm for q,k (+scale),
// cast bf16, scatter to qn/kn/v in [B,H,S,32] layout.
// Grid: (24 n-tiles, 512 m-tiles), 256 threads.
// ---------------------------------------------------------------------------
__global__ __launch_bounds__(256) void qkv_kernel(
    const float* __restrict__ hs, const float* __restrict__ Wqkv,
    const float* __restrict__ bqkv, const float* __restrict__ lsc,
    __bf16* __restrict__ qn, __bf16* __restrict__ kn, __bf16* __restrict__ vv)
{
    __shared__ __align__(16) char smem[18432];
    __bf16 (*As)[72] = (__bf16(*)[72])smem;
    __bf16 (*Bs)[72] = (__bf16(*)[72])(smem + 9216);
    float  (*Cs)[68] = (float(*)[68])smem;

    const int t = threadIdx.x;
    const int mBase = blockIdx.y * 64;
    const int nBase = blockIdx.x * 64;
    const int wave = t >> 6, lane = t & 63;
    const int wr = wave >> 1, wc = wave & 1;
    const int lhi = lane >> 4, llo = lane & 15;
    const int srow = t >> 2, sseg = (t & 3) * 16;

    const float* pa = hs   + (size_t)(mBase + srow) * 512 + sseg;
    const float* pb = Wqkv + (size_t)(nBase + srow) * 512 + sseg;

    f32x4 acc[2][2] = {};

    for (int k0 = 0; k0 < 512; k0 += 64) {
        float4 ra[4], rb[4];
        #pragma unroll
        for (int j = 0; j < 4; ++j) {
            ra[j] = *(const float4*)(pa + k0 + j*4);
            rb[j] = *(const float4*)(pb + k0 + j*4);
        }
        __syncthreads();
        *(bf16x8*)&As[srow][sseg]     = pack8(ra[0], ra[1]);
        *(bf16x8*)&As[srow][sseg + 8] = pack8(ra[2], ra[3]);
        *(bf16x8*)&Bs[srow][sseg]     = pack8(rb[0], rb[1]);
        *(bf16x8*)&Bs[srow][sseg + 8] = pack8(rb[2], rb[3]);
        __syncthreads();
        #pragma unroll
        for (int kk = 0; kk < 64; kk += 32) {
            bf16x8 af[2], bg[2];
            #pragma unroll
            for (int i = 0; i < 2; ++i) {
                af[i] = *(const bf16x8*)&As[wr*32 + i*16 + llo][kk + lhi*8];
                bg[i] = *(const bf16x8*)&Bs[wc*32 + i*16 + llo][kk + lhi*8];
            }
            #pragma unroll
            for (int mi = 0; mi < 2; ++mi)
                #pragma unroll
                for (int ni = 0; ni < 2; ++ni)
                    acc[mi][ni] = MFMA_BF16(af[mi], bg[ni], acc[mi][ni], 0, 0, 0);
        }
    }

    __syncthreads();
    #pragma unroll
    for (int mi = 0; mi < 2; ++mi)
      #pragma unroll
      for (int ni = 0; ni < 2; ++ni) {
        float bn = bqkv[nBase + wc*32 + ni*16 + llo];
        #pragma unroll
        for (int r = 0; r < 4; ++r)
            Cs[wr*32 + mi*16 + lhi*4 + r][wc*32 + ni*16 + llo] = acc[mi][ni][r] + bn;
      }
    __syncthreads();

    // normalize + store: 128 groups of (row, head) x 2 threads each
    const int which = nBase >> 9;        // 0=q, 1=k, 2=v
    const int g = t >> 1, sub = t & 1;
    const int row = g >> 1, hloc = g & 1;
    const int cb = hloc*32 + sub*16;

    float vals[16];
    #pragma unroll
    for (int j = 0; j < 16; ++j) vals[j] = Cs[row][cb + j];

    float f = 1.0f;
    if (which < 2) {
        float ss = 0.f;
        #pragma unroll
        for (int j = 0; j < 16; ++j) ss += vals[j]*vals[j];
        ss += __shfl_xor(ss, 1);
        f = 1.0f / fmaxf(sqrtf(ss), 1e-12f);
    }
    const int h = ((nBase & 511) >> 5) + hloc;
    if (which == 0) f *= expf(fminf(lsc[h], 4.6051701859880914f)); // log(100)

    const int m = mBase + row;
    const int b = m >> 8, s = m & 255;
    __bf16* outp = (which == 0) ? qn : (which == 1) ? kn : vv;
    __bf16* dst = outp + (((size_t)(b*16 + h)) * 256 + s) * 32 + sub*16;
    bf16x8 o0, o1;
    #pragma unroll
    for (int j = 0; j < 8; ++j) {
        o0[j] = (__bf16)(vals[j]   * f);
        o1[j] = (__bf16)(vals[j+8] * f);
    }
    *(bf16x8*)dst       = o0;
    *(bf16x8*)(dst + 8) = o1;
}

// ---------------------------------------------------------------------------
// Kernel 2a: bias_table[e][h] = (relu(coords[e] @ w1^T + b1)) @ w2^T
// Grid: 1575 blocks x 256 threads.
// ---------------------------------------------------------------------------
__global__ __launch_bounds__(256) void cpb_table_kernel(
    const float* __restrict__ w1, const float* __restrict__ b1,
    const float* __restrict__ w2, const float* __restrict__ coords,
    float* __restrict__ bias_table)
{
    __shared__ float hid[512];
    __shared__ float part[16][17];
    const int e = blockIdx.x;
    const float x = coords[e*3+0], y = coords[e*3+1], z = coords[e*3+2];
    const int t = threadIdx.x;
    for (int c = t; c < 512; c += 256) {
        float v = w1[c*3+0]*x + w1[c*3+1]*y + w1[c*3+2]*z + b1[c];
        hid[c] = fmaxf(v, 0.f);
    }
    __syncthreads();
    const int hh = t >> 4, seg = t & 15;
    float p = 0.f;
    #pragma unroll
    for (int j = 0; j < 32; ++j) p += w2[hh*512 + seg*32 + j] * hid[seg*32 + j];
    part[hh][seg] = p;
    __syncthreads();
    if (t < 16) {
        float s = 0.f;
        #pragma unroll
        for (int i = 0; i < 16; ++i) s += part[t][i];
        bias_table[e*16 + t] = s;
    }
}

// ---------------------------------------------------------------------------
// Kernel 2b: bias[h][i][j] = 16*sigmoid(bias_table[rel_index[ij]][h])
// Grid: 4096 x 256 (exactly 16*65536 threads).
// ---------------------------------------------------------------------------
__global__ __launch_bounds__(256) void bias_gather_kernel(
    const float* __restrict__ bias_table, const int* __restrict__ rel_index,
    float* __restrict__ bias)
{
    const int t = blockIdx.x * 256 + threadIdx.x;
    const int h = t >> 16, ij = t & 65535;
    const float v = bias_table[rel_index[ij]*16 + h];
    bias[t] = 16.f / (1.f + expf(-v));
}

// ---------------------------------------------------------------------------
// Kernel 3: attention per (b,h). K,V^T staged in LDS, per-16-row Q tiles:
// QK^T (16 MFMA) + bias, in-register softmax, P->LDS bf16, PV (16 MFMA).
// Grid: 2048 blocks x 256 threads (4 waves x 4 q-tiles each).
// ---------------------------------------------------------------------------
__global__ __launch_bounds__(256) void attn_kernel(
    const __bf16* __restrict__ qn, const __bf16* __restrict__ kn,
    const __bf16* __restrict__ vv, const float* __restrict__ bias,
    __bf16* __restrict__ ctx)
{
    __shared__ __align__(16) __bf16 Kl[256][40];    // pad 40: 80B stride, <=2-way
    __shared__ __align__(16) __bf16 Vt[32][264];    // V transposed, 528B stride
    __shared__ __align__(16) __bf16 Pl[4][16][264]; // per-wave P tile

    const int bh = blockIdx.x;
    const int b = bh >> 4, h = bh & 15;
    const int t = threadIdx.x;
    const int wave = t >> 6, lane = t & 63;
    const int lhi = lane >> 4, llo = lane & 15;

    const size_t base = (size_t)bh * 256 * 32;

    // stage K rows and V transposed
    {
        const __bf16* sk = kn + base + t*32;
        #pragma unroll
        for (int j = 0; j < 4; ++j)
            *(bf16x8*)&Kl[t][j*8] = *(const bf16x8*)(sk + j*8);
        const __bf16* sv = vv + base + t*32;
        #pragma unroll
        for (int j = 0; j < 4; ++j) {
            bf16x8 v8 = *(const bf16x8*)(sv + j*8);
            #pragma unroll
            for (int e = 0; e < 8; ++e) Vt[j*8 + e][t] = v8[e];
        }
    }
    __syncthreads();

    const float* bp_base = bias + ((size_t)h << 16);

    #pragma unroll 1
    for (int qt = 0; qt < 4; ++qt) {
        const int row0 = (wave*4 + qt) * 16;
        bf16x8 aq = *(const bf16x8*)(qn + base + (size_t)(row0 + llo)*32 + lhi*8);

        f32x4 sc[16];
        #pragma unroll
        for (int fc = 0; fc < 16; ++fc) {
            bf16x8 bk = *(const bf16x8*)&Kl[fc*16 + llo][lhi*8];
            f32x4 z = {0.f, 0.f, 0.f, 0.f};
            sc[fc] = MFMA_BF16(aq, bk, z, 0, 0, 0);
        }
        const float* bp = bp_base + (size_t)(row0 + lhi*4)*256 + llo;
        #pragma unroll
        for (int fc = 0; fc < 16; ++fc)
            #pragma unroll
            for (int r = 0; r < 4; ++r)
                sc[fc][r] += bp[(size_t)r*256 + fc*16];

        float mx[4], inv[4];
        #pragma unroll
        for (int r = 0; r < 4; ++r) {
            float m0 = sc[0][r];
            #pragma unroll
            for (int fc = 1; fc < 16; ++fc) m0 = fmaxf(m0, sc[fc][r]);
            m0 = fmaxf(m0, __shfl_xor(m0, 1));
            m0 = fmaxf(m0, __shfl_xor(m0, 2));
            m0 = fmaxf(m0, __shfl_xor(m0, 4));
            m0 = fmaxf(m0, __shfl_xor(m0, 8));
            mx[r] = m0;
        }
        #pragma unroll
        for (int fc = 0; fc < 16; ++fc)
            #pragma unroll
            for (int r = 0; r < 4; ++r)
                sc[fc][r] = expf(sc[fc][r] - mx[r]);
        #pragma unroll
        for (int r = 0; r < 4; ++r) {
            float s0 = 0.f;
            #pragma unroll
            for (int fc = 0; fc < 16; ++fc) s0 += sc[fc][r];
            s0 += __shfl_xor(s0, 1);
            s0 += __shfl_xor(s0, 2);
            s0 += __shfl_xor(s0, 4);
            s0 += __shfl_xor(s0, 8);
            inv[r] = 1.0f / s0;
        }
        // P -> LDS (bf16), per-wave region, no barrier needed (wave-local)
        #pragma unroll
        for (int fc = 0; fc < 16; ++fc)
            #pragma unroll
            for (int r = 0; r < 4; ++r)
                Pl[wave][lhi*4 + r][fc*16 + llo] = (__bf16)sc[fc][r];
        // PV
        f32x4 o[2] = {};
        #pragma unroll
        for (int k0 = 0; k0 < 8; ++k0) {
            bf16x8 ap = *(const bf16x8*)&Pl[wave][llo][k0*32 + lhi*8];
            #pragma unroll
            for (int nf = 0; nf < 2; ++nf) {
                bf16x8 bv = *(const bf16x8*)&Vt[nf*16 + llo][k0*32 + lhi*8];
                o[nf] = MFMA_BF16(ap, bv, o[nf], 0, 0, 0);
            }
        }
        // store ctx [B,S,512] bf16 with 1/sum folded in
        #pragma unroll
        for (int nf = 0; nf < 2; ++nf)
            #pragma unroll
            for (int r = 0; r < 4; ++r) {
                int srow = row0 + lhi*4 + r;
                ctx[((size_t)(b*256 + srow))*512 + h*32 + nf*16 + llo]
                    = (__bf16)(o[nf][r] * inv[r]);
            }
    }
}

// ---------------------------------------------------------------------------
// Kernel 4: out = ctx @ Wproj^T + bproj  (fp32 out, direct coalesced stores)
// Grid: (8 n-tiles, 512 m-tiles), 256 threads.
// ---------------------------------------------------------------------------
__global__ __launch_bounds__(256) void proj_kernel(
    const __bf16* __restrict__ ctx, const float* __restrict__ Wp,
    const float* __restrict__ bpr, float* __restrict__ out)
{
    __shared__ __align__(16) __bf16 As[64][72];
    __shared__ __align__(16) __bf16 Bs[64][72];

    const int t = threadIdx.x;
    const int mBase = blockIdx.y * 64, nBase = blockIdx.x * 64;
    const int wave = t >> 6, lane = t & 63;
    const int wr = wave >> 1, wc = wave & 1;
    const int lhi = lane >> 4, llo = lane & 15;
    const int srow = t >> 2, sseg = (t & 3) * 16;

    const __bf16* pa = ctx + (size_t)(mBase + srow)*512 + sseg;
    const float*  pb = Wp  + (size_t)(nBase + srow)*512 + sseg;

    f32x4 acc[2][2] = {};
    for (int k0 = 0; k0 < 512; k0 += 64) {
        bf16x8 ra0 = *(const bf16x8*)(pa + k0);
        bf16x8 ra1 = *(const bf16x8*)(pa + k0 + 8);
        float4 rb[4];
        #pragma unroll
        for (int j = 0; j < 4; ++j) rb[j] = *(const float4*)(pb + k0 + j*4);
        __syncthreads();
        *(bf16x8*)&As[srow][sseg]     = ra0;
        *(bf16x8*)&As[srow][sseg + 8] = ra1;
        *(bf16x8*)&Bs[srow][sseg]     = pack8(rb[0], rb[1]);
        *(bf16x8*)&Bs[srow][sseg + 8] = pack8(rb[2], rb[3]);
        __syncthreads();
        #pragma unroll
        for (int kk = 0; kk < 64; kk += 32) {
            bf16x8 af[2], bg[2];
            #pragma unroll
            for (int i = 0; i < 2; ++i) {
                af[i] = *(const bf16x8*)&As[wr*32 + i*16 + llo][kk + lhi*8];
                bg[i] = *(const bf16x8*)&Bs[wc*32 + i*16 + llo][kk + lhi*8];
            }
            #pragma unroll
            for (int mi = 0; mi < 2; ++mi)
                #pragma unroll
                for (int ni = 0; ni < 2; ++ni)
                    acc[mi][ni] = MFMA_BF16(af[mi], bg[ni], acc[mi][ni], 0, 0, 0);
        }
    }
    #pragma unroll
    for (int ni = 0; ni < 2; ++ni) {
        float bn = bpr[nBase + wc*32 + ni*16 + llo];
        #pragma unroll
        for (int mi = 0; mi < 2; ++mi)
            #pragma unroll
            for (int r = 0; r < 4; ++r)
                out[(size_t)(mBase + wr*32 + mi*16 + lhi*4 + r)*512
                    + nBase + wc*32 + ni*16 + llo] = acc[mi][ni][r] + bn;
    }
}

// ---------------------------------------------------------------------------
extern "C" void kernel_launch(void* const* d_in, const int* in_sizes, int n_in,
                              void* d_out, int out_size, void* d_ws, size_t ws_size,
                              hipStream_t stream) {
    const float* hs     = (const float*)d_in[0];
    const float* Wqkv   = (const float*)d_in[1];
    const float* bqkv   = (const float*)d_in[2];
    const float* Wproj  = (const float*)d_in[3];
    const float* bproj  = (const float*)d_in[4];
    const float* lsc    = (const float*)d_in[5];
    const float* cpb_w1 = (const float*)d_in[6];
    const float* cpb_b1 = (const float*)d_in[7];
    const float* cpb_w2 = (const float*)d_in[8];
    const float* coords = (const float*)d_in[9];
    const int*   relidx = (const int*)d_in[10];
    float* out = (float*)d_out;

    char* ws = (char*)d_ws;
    __bf16* qn   = (__bf16*)(ws);                 // 33554432 B
    __bf16* kn   = (__bf16*)(ws + 33554432);      // 33554432 B
    __bf16* vv   = (__bf16*)(ws + 67108864);      // 33554432 B
    __bf16* ctx  = (__bf16*)(ws + 100663296);     // 33554432 B
    float*  bt   = (float*)(ws + 134217728);      // 100800 B
    float*  bias = (float*)(ws + 134318528);      // 4194304 B -> total ~138.5 MB

    qkv_kernel<<<dim3(24, 512), 256, 0, stream>>>(hs, Wqkv, bqkv, lsc, qn, kn, vv);
    cpb_table_kernel<<<1575, 256, 0, stream>>>(cpb_w1, cpb_b1, cpb_w2, coords, bt);
    bias_gather_kernel<<<4096, 256, 0, stream>>>(bt, relidx, bias);
    attn_kernel<<<2048, 256, 0, stream>>>(qn, kn, vv, bias, ctx);
    proj_kernel<<<dim3(8, 512), 256, 0, stream>>>(ctx, Wproj, bproj, out);
}

// Round 5
// 427.353 us; speedup vs baseline: 1.4502x; 1.4502x over previous
//
#include <hip/hip_runtime.h>
#include <hip/hip_bf16.h>

typedef __bf16 bf16x8 __attribute__((ext_vector_type(8)));
typedef __bf16 bf16x4 __attribute__((ext_vector_type(4)));
typedef float  f32x4  __attribute__((ext_vector_type(4)));

#define MFMA_BF16 __builtin_amdgcn_mfma_f32_16x16x32_bf16

static __device__ __forceinline__ bf16x8 pack8(float4 a, float4 b) {
    bf16x8 r;
    r[0] = (__bf16)a.x; r[1] = (__bf16)a.y; r[2] = (__bf16)a.z; r[3] = (__bf16)a.w;
    r[4] = (__bf16)b.x; r[5] = (__bf16)b.y; r[6] = (__bf16)b.z; r[7] = (__bf16)b.w;
    return r;
}

// ---------------------------------------------------------------------------
// Kernel 1: qkv = hs @ Wqkv^T + bqkv, per-head L2 norm for q,k (+scale),
// bf16 out in [B,H,S,32] layout. (r1-proven, unchanged)
// ---------------------------------------------------------------------------
__global__ __launch_bounds__(256) void qkv_kernel(
    const float* __restrict__ hs, const float* __restrict__ Wqkv,
    const float* __restrict__ bqkv, const float* __restrict__ lsc,
    __bf16* __restrict__ qn, __bf16* __restrict__ kn, __bf16* __restrict__ vv)
{
    __shared__ __align__(16) char smem[18432];
    __bf16 (*As)[72] = (__bf16(*)[72])smem;
    __bf16 (*Bs)[72] = (__bf16(*)[72])(smem + 9216);
    float  (*Cs)[68] = (float(*)[68])smem;

    const int t = threadIdx.x;
    const int mBase = blockIdx.y * 64;
    const int nBase = blockIdx.x * 64;
    const int wave = t >> 6, lane = t & 63;
    const int wr = wave >> 1, wc = wave & 1;
    const int lhi = lane >> 4, llo = lane & 15;
    const int srow = t >> 2, sseg = (t & 3) * 16;

    const float* pa = hs   + (size_t)(mBase + srow) * 512 + sseg;
    const float* pb = Wqkv + (size_t)(nBase + srow) * 512 + sseg;

    f32x4 acc[2][2] = {};

    for (int k0 = 0; k0 < 512; k0 += 64) {
        float4 ra[4], rb[4];
        #pragma unroll
        for (int j = 0; j < 4; ++j) {
            ra[j] = *(const float4*)(pa + k0 + j*4);
            rb[j] = *(const float4*)(pb + k0 + j*4);
        }
        __syncthreads();
        *(bf16x8*)&As[srow][sseg]     = pack8(ra[0], ra[1]);
        *(bf16x8*)&As[srow][sseg + 8] = pack8(ra[2], ra[3]);
        *(bf16x8*)&Bs[srow][sseg]     = pack8(rb[0], rb[1]);
        *(bf16x8*)&Bs[srow][sseg + 8] = pack8(rb[2], rb[3]);
        __syncthreads();
        #pragma unroll
        for (int kk = 0; kk < 64; kk += 32) {
            bf16x8 af[2], bg[2];
            #pragma unroll
            for (int i = 0; i < 2; ++i) {
                af[i] = *(const bf16x8*)&As[wr*32 + i*16 + llo][kk + lhi*8];
                bg[i] = *(const bf16x8*)&Bs[wc*32 + i*16 + llo][kk + lhi*8];
            }
            #pragma unroll
            for (int mi = 0; mi < 2; ++mi)
                #pragma unroll
                for (int ni = 0; ni < 2; ++ni)
                    acc[mi][ni] = MFMA_BF16(af[mi], bg[ni], acc[mi][ni], 0, 0, 0);
        }
    }

    __syncthreads();
    #pragma unroll
    for (int mi = 0; mi < 2; ++mi)
      #pragma unroll
      for (int ni = 0; ni < 2; ++ni) {
        float bn = bqkv[nBase + wc*32 + ni*16 + llo];
        #pragma unroll
        for (int r = 0; r < 4; ++r)
            Cs[wr*32 + mi*16 + lhi*4 + r][wc*32 + ni*16 + llo] = acc[mi][ni][r] + bn;
      }
    __syncthreads();

    const int which = nBase >> 9;        // 0=q, 1=k, 2=v
    const int g = t >> 1, sub = t & 1;
    const int row = g >> 1, hloc = g & 1;
    const int cb = hloc*32 + sub*16;

    float vals[16];
    #pragma unroll
    for (int j = 0; j < 16; ++j) vals[j] = Cs[row][cb + j];

    float f = 1.0f;
    if (which < 2) {
        float ss = 0.f;
        #pragma unroll
        for (int j = 0; j < 16; ++j) ss += vals[j]*vals[j];
        ss += __shfl_xor(ss, 1);
        f = 1.0f / fmaxf(sqrtf(ss), 1e-12f);
    }
    const int h = ((nBase & 511) >> 5) + hloc;
    if (which == 0) f *= expf(fminf(lsc[h], 4.6051701859880914f)); // log(100)

    const int m = mBase + row;
    const int b = m >> 8, s = m & 255;
    __bf16* outp = (which == 0) ? qn : (which == 1) ? kn : vv;
    __bf16* dst = outp + (((size_t)(b*16 + h)) * 256 + s) * 32 + sub*16;
    bf16x8 o0, o1;
    #pragma unroll
    for (int j = 0; j < 8; ++j) {
        o0[j] = (__bf16)(vals[j]   * f);
        o1[j] = (__bf16)(vals[j+8] * f);
    }
    *(bf16x8*)dst       = o0;
    *(bf16x8*)(dst + 8) = o1;
}

// ---------------------------------------------------------------------------
// Kernel 2a: bias_table[e][h] = (relu(coords[e] @ w1^T + b1)) @ w2^T
// ---------------------------------------------------------------------------
__global__ __launch_bounds__(256) void cpb_table_kernel(
    const float* __restrict__ w1, const float* __restrict__ b1,
    const float* __restrict__ w2, const float* __restrict__ coords,
    float* __restrict__ bias_table)
{
    __shared__ float hid[512];
    __shared__ float part[16][17];
    const int e = blockIdx.x;
    const float x = coords[e*3+0], y = coords[e*3+1], z = coords[e*3+2];
    const int t = threadIdx.x;
    for (int c = t; c < 512; c += 256) {
        float v = w1[c*3+0]*x + w1[c*3+1]*y + w1[c*3+2]*z + b1[c];
        hid[c] = fmaxf(v, 0.f);
    }
    __syncthreads();
    const int hh = t >> 4, seg = t & 15;
    float p = 0.f;
    #pragma unroll
    for (int j = 0; j < 32; ++j) p += w2[hh*512 + seg*32 + j] * hid[seg*32 + j];
    part[hh][seg] = p;
    __syncthreads();
    if (t < 16) {
        float s = 0.f;
        #pragma unroll
        for (int i = 0; i < 16; ++i) s += part[t][i];
        bias_table[e*16 + t] = s;
    }
}

// ---------------------------------------------------------------------------
// Kernel 2b: bias in TRANSPOSED MFMA C-fragment layout (for swapped QK^T):
// tile (i16 = q-tile, j16 = k-tile); lane reg r holds value for
//   q = i16*16 + (lane&15),  k = j16*16 + (lane>>4)*4 + r
// A constant -26 (logit upper bound) is folded in so exp(s) <= 1.
// Grid: 1024 x 256.
// ---------------------------------------------------------------------------
__global__ __launch_bounds__(256) void bias_gather_kernel(
    const float* __restrict__ bias_table, const int* __restrict__ rel_index,
    float* __restrict__ bias_f)
{
    const int tid = blockIdx.x * 256 + threadIdx.x;   // 262144 total
    const int lane = tid & 63;
    const int j16 = (tid >> 6) & 15;
    const int i16 = (tid >> 10) & 15;
    const int h   = tid >> 14;
    const int llo = lane & 15, lhi = lane >> 4;
    const int qrow = i16*16 + llo;
    float4 o;
    #pragma unroll
    for (int r = 0; r < 4; ++r) {
        int kcol = j16*16 + lhi*4 + r;
        int idx = rel_index[qrow*256 + kcol];
        float v = bias_table[idx*16 + h];
        (&o.x)[r] = 16.f / (1.f + __expf(-v)) - 26.0f;
    }
    ((float4*)bias_f)[tid] = o;
}

// ---------------------------------------------------------------------------
// Kernel 3: attention per (b,h). Swapped QK^T: st = mfma(A=K, B=Q, C=bias^T)
// puts all of one q-row's scores in one lane -> P stays in registers.
// V^T staged with permuted columns (slot p(u)=8*((u&15)>>2)+(u&3)+((u>>4)&1)*4)
// so the PV B-frag k-order matches the in-register P k-order.
// Grid: 2048 blocks x 256 threads (4 waves x 4 q-tiles each).
// ---------------------------------------------------------------------------
__global__ __launch_bounds__(256) void attn_kernel(
    const __bf16* __restrict__ qn, const __bf16* __restrict__ kn,
    const __bf16* __restrict__ vv, const float* __restrict__ bias_f,
    __bf16* __restrict__ ctx)
{
    __shared__ __align__(16) __bf16 Kl[256][40];    // 20480 B
    __shared__ __align__(16) __bf16 Vt[32][264];    // 16896 B  -> 37376 total

    const int bh = blockIdx.x;
    const int b = bh >> 4, h = bh & 15;
    const int t = threadIdx.x;
    const int wave = t >> 6, lane = t & 63;
    const int lhi = lane >> 4, llo = lane & 15;
    const size_t base = (size_t)bh * 8192;          // 256*32

    // stage K rows (natural order) and V transposed with permuted columns
    {
        const __bf16* sk = kn + base + t*32;
        #pragma unroll
        for (int j = 0; j < 4; ++j)
            *(bf16x8*)&Kl[t][j*8] = *(const bf16x8*)(sk + j*8);

        const int u = t & 31;
        const int slot = (t & ~31) + 8*((u & 15) >> 2) + (u & 3) + ((u >> 4) & 1)*4;
        const __bf16* sv = vv + base + t*32;
        #pragma unroll
        for (int j = 0; j < 4; ++j) {
            bf16x8 v8 = *(const bf16x8*)(sv + j*8);
            #pragma unroll
            for (int e = 0; e < 8; ++e) Vt[j*8 + e][slot] = v8[e];
        }
    }
    __syncthreads();

    const f32x4* bp4 = (const f32x4*)bias_f + (size_t)h * 16384;  // h*16*16*64

    #pragma unroll 1
    for (int qt = 0; qt < 4; ++qt) {
        const int i16 = wave*4 + qt;
        const int row0 = i16*16;
        // B-frag: Q[q=llo][d=lhi*8+j]
        bf16x8 bq = *(const bf16x8*)(qn + base + (size_t)(row0 + llo)*32 + lhi*8);

        f32x4 o0 = {0.f,0.f,0.f,0.f}, o1 = {0.f,0.f,0.f,0.f};
        float sum = 0.f;

        #pragma unroll 2
        for (int c = 0; c < 8; ++c) {
            f32x4 bfA = bp4[((size_t)i16*16 + 2*c    )*64 + lane];
            f32x4 bfB = bp4[((size_t)i16*16 + 2*c + 1)*64 + lane];

            // A-frags: K rows 32c+llo and 32c+16+llo
            bf16x8 ka0 = *(const bf16x8*)&Kl[c*32 + llo][lhi*8];
            bf16x8 ka1 = *(const bf16x8*)&Kl[c*32 + 16 + llo][lhi*8];

            __builtin_amdgcn_s_setprio(1);
            f32x4 stA = MFMA_BF16(ka0, bq, bfA, 0, 0, 0);  // S^T[k][q] + bias - 26
            f32x4 stB = MFMA_BF16(ka1, bq, bfB, 0, 0, 0);
            __builtin_amdgcn_s_setprio(0);

            // P in registers: lane holds q=llo, k = {32c+4*lhi+r} u {32c+16+4*lhi+r}
            bf16x8 pa;
            #pragma unroll
            for (int r = 0; r < 4; ++r) {
                float eA = __expf(stA[r]);
                float eB = __expf(stB[r]);
                sum += eA + eB;
                pa[r]     = (__bf16)eA;
                pa[r + 4] = (__bf16)eB;
            }

            // B-frags: permuted V^T columns match pa's k-order
            bf16x8 bv0 = *(const bf16x8*)&Vt[llo][c*32 + lhi*8];
            bf16x8 bv1 = *(const bf16x8*)&Vt[16 + llo][c*32 + lhi*8];

            __builtin_amdgcn_s_setprio(1);
            o0 = MFMA_BF16(pa, bv0, o0, 0, 0, 0);   // D[q][d], d 0..15
            o1 = MFMA_BF16(pa, bv1, o1, 0, 0, 0);   // d 16..31
            __builtin_amdgcn_s_setprio(0);
        }

        // full row-sum for q=llo (reduce over lhi groups), then redistribute
        sum += __shfl_xor(sum, 16);
        sum += __shfl_xor(sum, 32);

        #pragma unroll
        for (int r = 0; r < 4; ++r) {
            float inv = __builtin_amdgcn_rcpf(__shfl(sum, lhi*4 + r));
            int srow = row0 + lhi*4 + r;
            __bf16* cp = ctx + ((size_t)(b*256 + srow))*512 + h*32;
            cp[llo]      = (__bf16)(o0[r] * inv);
            cp[16 + llo] = (__bf16)(o1[r] * inv);
        }
    }
}

// ---------------------------------------------------------------------------
// Kernel 4: out = ctx @ Wproj^T + bproj (r1-proven, unchanged)
// ---------------------------------------------------------------------------
__global__ __launch_bounds__(256) void proj_kernel(
    const __bf16* __restrict__ ctx, const float* __restrict__ Wp,
    const float* __restrict__ bpr, float* __restrict__ out)
{
    __shared__ __align__(16) __bf16 As[64][72];
    __shared__ __align__(16) __bf16 Bs[64][72];

    const int t = threadIdx.x;
    const int mBase = blockIdx.y * 64, nBase = blockIdx.x * 64;
    const int wave = t >> 6, lane = t & 63;
    const int wr = wave >> 1, wc = wave & 1;
    const int lhi = lane >> 4, llo = lane & 15;
    const int srow = t >> 2, sseg = (t & 3) * 16;

    const __bf16* pa = ctx + (size_t)(mBase + srow)*512 + sseg;
    const float*  pb = Wp  + (size_t)(nBase + srow)*512 + sseg;

    f32x4 acc[2][2] = {};
    for (int k0 = 0; k0 < 512; k0 += 64) {
        bf16x8 ra0 = *(const bf16x8*)(pa + k0);
        bf16x8 ra1 = *(const bf16x8*)(pa + k0 + 8);
        float4 rb[4];
        #pragma unroll
        for (int j = 0; j < 4; ++j) rb[j] = *(const float4*)(pb + k0 + j*4);
        __syncthreads();
        *(bf16x8*)&As[srow][sseg]     = ra0;
        *(bf16x8*)&As[srow][sseg + 8] = ra1;
        *(bf16x8*)&Bs[srow][sseg]     = pack8(rb[0], rb[1]);
        *(bf16x8*)&Bs[srow][sseg + 8] = pack8(rb[2], rb[3]);
        __syncthreads();
        #pragma unroll
        for (int kk = 0; kk < 64; kk += 32) {
            bf16x8 af[2], bg[2];
            #pragma unroll
            for (int i = 0; i < 2; ++i) {
                af[i] = *(const bf16x8*)&As[wr*32 + i*16 + llo][kk + lhi*8];
                bg[i] = *(const bf16x8*)&Bs[wc*32 + i*16 + llo][kk + lhi*8];
            }
            #pragma unroll
            for (int mi = 0; mi < 2; ++mi)
                #pragma unroll
                for (int ni = 0; ni < 2; ++ni)
                    acc[mi][ni] = MFMA_BF16(af[mi], bg[ni], acc[mi][ni], 0, 0, 0);
        }
    }
    #pragma unroll
    for (int ni = 0; ni < 2; ++ni) {
        float bn = bpr[nBase + wc*32 + ni*16 + llo];
        #pragma unroll
        for (int mi = 0; mi < 2; ++mi)
            #pragma unroll
            for (int r = 0; r < 4; ++r)
                out[(size_t)(mBase + wr*32 + mi*16 + lhi*4 + r)*512
                    + nBase + wc*32 + ni*16 + llo] = acc[mi][ni][r] + bn;
    }
}

// ---------------------------------------------------------------------------
extern "C" void kernel_launch(void* const* d_in, const int* in_sizes, int n_in,
                              void* d_out, int out_size, void* d_ws, size_t ws_size,
                              hipStream_t stream) {
    const float* hs     = (const float*)d_in[0];
    const float* Wqkv   = (const float*)d_in[1];
    const float* bqkv   = (const float*)d_in[2];
    const float* Wproj  = (const float*)d_in[3];
    const float* bproj  = (const float*)d_in[4];
    const float* lsc    = (const float*)d_in[5];
    const float* cpb_w1 = (const float*)d_in[6];
    const float* cpb_b1 = (const float*)d_in[7];
    const float* cpb_w2 = (const float*)d_in[8];
    const float* coords = (const float*)d_in[9];
    const int*   relidx = (const int*)d_in[10];
    float* out = (float*)d_out;

    char* ws = (char*)d_ws;
    __bf16* qn     = (__bf16*)(ws);                 // 33554432 B
    __bf16* kn     = (__bf16*)(ws + 33554432);      // 33554432 B
    __bf16* vv     = (__bf16*)(ws + 67108864);      // 33554432 B
    __bf16* ctx    = (__bf16*)(ws + 100663296);     // 33554432 B
    float*  bt     = (float*)(ws + 134217728);      // 100800 B
    float*  bias_f = (float*)(ws + 134318528);      // 4194304 B

    qkv_kernel<<<dim3(24, 512), 256, 0, stream>>>(hs, Wqkv, bqkv, lsc, qn, kn, vv);
    cpb_table_kernel<<<1575, 256, 0, stream>>>(cpb_w1, cpb_b1, cpb_w2, coords, bt);
    bias_gather_kernel<<<1024, 256, 0, stream>>>(bt, relidx, bias_f);
    attn_kernel<<<2048, 256, 0, stream>>>(qn, kn, vv, bias_f, ctx);
    proj_kernel<<<dim3(8, 512), 256, 0, stream>>>(ctx, Wproj, bproj, out);
}

// Round 6
// 362.919 us; speedup vs baseline: 1.7076x; 1.1775x over previous
//
#include <hip/hip_runtime.h>
#include <hip/hip_bf16.h>

typedef __bf16 bf16x8 __attribute__((ext_vector_type(8)));
typedef float  f32x4  __attribute__((ext_vector_type(4)));

#define MFMA_BF16 __builtin_amdgcn_mfma_f32_16x16x32_bf16

static __device__ __forceinline__ bf16x8 pack8(float4 a, float4 b) {
    bf16x8 r;
    r[0] = (__bf16)a.x; r[1] = (__bf16)a.y; r[2] = (__bf16)a.z; r[3] = (__bf16)a.w;
    r[4] = (__bf16)b.x; r[5] = (__bf16)b.y; r[6] = (__bf16)b.z; r[7] = (__bf16)b.w;
    return r;
}

static __device__ __forceinline__ void gload16(const void* g, void* l) {
    __builtin_amdgcn_global_load_lds(
        (const __attribute__((address_space(1))) unsigned int*)g,
        (__attribute__((address_space(3))) unsigned int*)l,
        16, 0, 0);
}

// ---------------------------------------------------------------------------
// Kernel 0: fp32 -> bf16 convert (8 elems/thread, exact grids)
// ---------------------------------------------------------------------------
__global__ __launch_bounds__(256) void cvt_bf16_kernel(
    const float* __restrict__ src, __bf16* __restrict__ dst)
{
    const size_t i = ((size_t)blockIdx.x * 256 + threadIdx.x) * 8;
    float4 a = *(const float4*)(src + i);
    float4 b = *(const float4*)(src + i + 4);
    *(bf16x8*)(dst + i) = pack8(a, b);
}

// ---------------------------------------------------------------------------
// Kernel 1: qkv GEMM, 128x128 tile, BK=64, global_load_lds staging (m97-style).
// Epilogue: +bias, per-(row,head) L2 norm via shfl butterfly, scale for q,
// bf16 scatter to [B,H,S,32]. Grid: (12 n-tiles, 256 m-tiles) x 256 thr.
// ---------------------------------------------------------------------------
__global__ __launch_bounds__(256) void qkv_kernel(
    const __bf16* __restrict__ hsb, const __bf16* __restrict__ Wqb,
    const float* __restrict__ bqkv, const float* __restrict__ lsc,
    __bf16* __restrict__ qn, __bf16* __restrict__ kn, __bf16* __restrict__ vv)
{
    __shared__ __align__(16) __bf16 As[128][64];   // 16 KB
    __shared__ __align__(16) __bf16 Bs[128][64];   // 16 KB

    const int t = threadIdx.x;
    const int nBase = blockIdx.x * 128;
    const int mBase = blockIdx.y * 128;
    const int wave = t >> 6, lane = t & 63;
    const int wr = wave >> 1, wc = wave & 1;
    const int lhi = lane >> 4, llo = lane & 15;
    const int srow = t >> 3;            // 0..31
    const int scol = (t & 7) * 8;       // element col (16B chunk)

    const __bf16* gA = hsb + (size_t)(mBase + srow) * 512 + scol;
    const __bf16* gB = Wqb + (size_t)(nBase + srow) * 512 + scol;
    char* lA = (char*)(&As[0][0]) + wave * 1024;
    char* lB = (char*)(&Bs[0][0]) + wave * 1024;

    f32x4 acc[4][4] = {};

    for (int k0 = 0; k0 < 512; k0 += 64) {
        __syncthreads();
        #pragma unroll
        for (int i = 0; i < 4; ++i) {
            gload16(gA + k0 + i * 16384, lA + i * 4096);   // 32 rows * 512
            gload16(gB + k0 + i * 16384, lB + i * 4096);
        }
        __syncthreads();
        #pragma unroll
        for (int kk = 0; kk < 64; kk += 32) {
            bf16x8 af[4], bg[4];
            #pragma unroll
            for (int x = 0; x < 4; ++x) {
                af[x] = *(const bf16x8*)&As[wr*64 + x*16 + llo][kk + lhi*8];
                bg[x] = *(const bf16x8*)&Bs[wc*64 + x*16 + llo][kk + lhi*8];
            }
            #pragma unroll
            for (int mi = 0; mi < 4; ++mi)
                #pragma unroll
                for (int ni = 0; ni < 4; ++ni)
                    acc[mi][ni] = MFMA_BF16(af[mi], bg[ni], acc[mi][ni], 0, 0, 0);
        }
    }

    // epilogue: C[row][col], row = mBase+wr*64+mi*16+lhi*4+r, col = nW+ni*16+llo
    const int nW = nBase + wc * 64;
    const int which = nW >> 9;          // 0=q, 1=k, 2=v (64-col span never crosses)
    __bf16* outp = (which == 0) ? qn : (which == 1) ? kn : vv;
    float bq[4];
    #pragma unroll
    for (int ni = 0; ni < 4; ++ni) bq[ni] = bqkv[nW + ni*16 + llo];

    #pragma unroll
    for (int p = 0; p < 2; ++p) {       // head-pair: frags (2p, 2p+1) = one head
        const int h = ((nW + p*32) >> 5) & 15;
        const float sc = (which == 0) ? __expf(fminf(lsc[h], 4.6051701859880914f))
                                      : 1.0f;
        #pragma unroll
        for (int mi = 0; mi < 4; ++mi) {
            #pragma unroll
            for (int r = 0; r < 4; ++r) {
                float v0 = acc[mi][2*p][r]   + bq[2*p];
                float v1 = acc[mi][2*p+1][r] + bq[2*p+1];
                float f = 1.0f;
                if (which < 2) {
                    float ss = v0*v0 + v1*v1;
                    ss += __shfl_xor(ss, 1);
                    ss += __shfl_xor(ss, 2);
                    ss += __shfl_xor(ss, 4);
                    ss += __shfl_xor(ss, 8);
                    f = sc / fmaxf(sqrtf(ss), 1e-12f);
                }
                const int row = mBase + wr*64 + mi*16 + lhi*4 + r;
                const int b = row >> 8, s = row & 255;
                __bf16* dst = outp + (((size_t)(b*16 + h))*256 + s)*32;
                dst[llo]      = (__bf16)(v0 * f);
                dst[16 + llo] = (__bf16)(v1 * f);
            }
        }
    }
}

// ---------------------------------------------------------------------------
// Kernel 2a: bias_table[e][h] = (relu(coords[e] @ w1^T + b1)) @ w2^T
// ---------------------------------------------------------------------------
__global__ __launch_bounds__(256) void cpb_table_kernel(
    const float* __restrict__ w1, const float* __restrict__ b1,
    const float* __restrict__ w2, const float* __restrict__ coords,
    float* __restrict__ bias_table)
{
    __shared__ float hid[512];
    __shared__ float part[16][17];
    const int e = blockIdx.x;
    const float x = coords[e*3+0], y = coords[e*3+1], z = coords[e*3+2];
    const int t = threadIdx.x;
    for (int c = t; c < 512; c += 256) {
        float v = w1[c*3+0]*x + w1[c*3+1]*y + w1[c*3+2]*z + b1[c];
        hid[c] = fmaxf(v, 0.f);
    }
    __syncthreads();
    const int hh = t >> 4, seg = t & 15;
    float p = 0.f;
    #pragma unroll
    for (int j = 0; j < 32; ++j) p += w2[hh*512 + seg*32 + j] * hid[seg*32 + j];
    part[hh][seg] = p;
    __syncthreads();
    if (t < 16) {
        float s = 0.f;
        #pragma unroll
        for (int i = 0; i < 16; ++i) s += part[t][i];
        bias_table[e*16 + t] = s;
    }
}

// ---------------------------------------------------------------------------
// Kernel 2b: bias in TRANSPOSED MFMA C-fragment layout (for swapped QK^T):
// lane reg r holds (q = i16*16 + (lane&15), k = j16*16 + (lane>>4)*4 + r),
// with -26 folded in so exp(s) <= 1.
// ---------------------------------------------------------------------------
__global__ __launch_bounds__(256) void bias_gather_kernel(
    const float* __restrict__ bias_table, const int* __restrict__ rel_index,
    float* __restrict__ bias_f)
{
    const int tid = blockIdx.x * 256 + threadIdx.x;   // 262144 total
    const int lane = tid & 63;
    const int j16 = (tid >> 6) & 15;
    const int i16 = (tid >> 10) & 15;
    const int h   = tid >> 14;
    const int llo = lane & 15, lhi = lane >> 4;
    const int qrow = i16*16 + llo;
    float4 o;
    #pragma unroll
    for (int r = 0; r < 4; ++r) {
        int kcol = j16*16 + lhi*4 + r;
        int idx = rel_index[qrow*256 + kcol];
        float v = bias_table[idx*16 + h];
        (&o.x)[r] = 16.f / (1.f + __expf(-v)) - 26.0f;
    }
    ((float4*)bias_f)[tid] = o;
}

// ---------------------------------------------------------------------------
// Kernel 3: attention per (b,h). Swapped QK^T (r4-proven, unchanged).
// ---------------------------------------------------------------------------
__global__ __launch_bounds__(256) void attn_kernel(
    const __bf16* __restrict__ qn, const __bf16* __restrict__ kn,
    const __bf16* __restrict__ vv, const float* __restrict__ bias_f,
    __bf16* __restrict__ ctx)
{
    __shared__ __align__(16) __bf16 Kl[256][40];    // 20480 B
    __shared__ __align__(16) __bf16 Vt[32][264];    // 16896 B

    const int bh = blockIdx.x;
    const int b = bh >> 4, h = bh & 15;
    const int t = threadIdx.x;
    const int wave = t >> 6, lane = t & 63;
    const int lhi = lane >> 4, llo = lane & 15;
    const size_t base = (size_t)bh * 8192;

    {
        const __bf16* sk = kn + base + t*32;
        #pragma unroll
        for (int j = 0; j < 4; ++j)
            *(bf16x8*)&Kl[t][j*8] = *(const bf16x8*)(sk + j*8);

        const int u = t & 31;
        const int slot = (t & ~31) + 8*((u & 15) >> 2) + (u & 3) + ((u >> 4) & 1)*4;
        const __bf16* sv = vv + base + t*32;
        #pragma unroll
        for (int j = 0; j < 4; ++j) {
            bf16x8 v8 = *(const bf16x8*)(sv + j*8);
            #pragma unroll
            for (int e = 0; e < 8; ++e) Vt[j*8 + e][slot] = v8[e];
        }
    }
    __syncthreads();

    const f32x4* bp4 = (const f32x4*)bias_f + (size_t)h * 16384;

    #pragma unroll 1
    for (int qt = 0; qt < 4; ++qt) {
        const int i16 = wave*4 + qt;
        const int row0 = i16*16;
        bf16x8 bq = *(const bf16x8*)(qn + base + (size_t)(row0 + llo)*32 + lhi*8);

        f32x4 o0 = {0.f,0.f,0.f,0.f}, o1 = {0.f,0.f,0.f,0.f};
        float sum = 0.f;

        #pragma unroll 2
        for (int c = 0; c < 8; ++c) {
            f32x4 bfA = bp4[((size_t)i16*16 + 2*c    )*64 + lane];
            f32x4 bfB = bp4[((size_t)i16*16 + 2*c + 1)*64 + lane];

            bf16x8 ka0 = *(const bf16x8*)&Kl[c*32 + llo][lhi*8];
            bf16x8 ka1 = *(const bf16x8*)&Kl[c*32 + 16 + llo][lhi*8];

            __builtin_amdgcn_s_setprio(1);
            f32x4 stA = MFMA_BF16(ka0, bq, bfA, 0, 0, 0);
            f32x4 stB = MFMA_BF16(ka1, bq, bfB, 0, 0, 0);
            __builtin_amdgcn_s_setprio(0);

            bf16x8 pa;
            #pragma unroll
            for (int r = 0; r < 4; ++r) {
                float eA = __expf(stA[r]);
                float eB = __expf(stB[r]);
                sum += eA + eB;
                pa[r]     = (__bf16)eA;
                pa[r + 4] = (__bf16)eB;
            }

            bf16x8 bv0 = *(const bf16x8*)&Vt[llo][c*32 + lhi*8];
            bf16x8 bv1 = *(const bf16x8*)&Vt[16 + llo][c*32 + lhi*8];

            __builtin_amdgcn_s_setprio(1);
            o0 = MFMA_BF16(pa, bv0, o0, 0, 0, 0);
            o1 = MFMA_BF16(pa, bv1, o1, 0, 0, 0);
            __builtin_amdgcn_s_setprio(0);
        }

        sum += __shfl_xor(sum, 16);
        sum += __shfl_xor(sum, 32);

        #pragma unroll
        for (int r = 0; r < 4; ++r) {
            float inv = __builtin_amdgcn_rcpf(__shfl(sum, lhi*4 + r));
            int srow = row0 + lhi*4 + r;
            __bf16* cp = ctx + ((size_t)(b*256 + srow))*512 + h*32;
            cp[llo]      = (__bf16)(o0[r] * inv);
            cp[16 + llo] = (__bf16)(o1[r] * inv);
        }
    }
}

// ---------------------------------------------------------------------------
// Kernel 4: out = ctx @ Wproj^T + bproj, 128x128 tile m97-style.
// Grid: (4 n-tiles, 256 m-tiles) x 256 threads.
// ---------------------------------------------------------------------------
__global__ __launch_bounds__(256) void proj_kernel(
    const __bf16* __restrict__ ctx, const __bf16* __restrict__ Wpb,
    const float* __restrict__ bpr, float* __restrict__ out)
{
    __shared__ __align__(16) __bf16 As[128][64];
    __shared__ __align__(16) __bf16 Bs[128][64];

    const int t = threadIdx.x;
    const int nBase = blockIdx.x * 128;
    const int mBase = blockIdx.y * 128;
    const int wave = t >> 6, lane = t & 63;
    const int wr = wave >> 1, wc = wave & 1;
    const int lhi = lane >> 4, llo = lane & 15;
    const int srow = t >> 3;
    const int scol = (t & 7) * 8;

    const __bf16* gA = ctx + (size_t)(mBase + srow) * 512 + scol;
    const __bf16* gB = Wpb + (size_t)(nBase + srow) * 512 + scol;
    char* lA = (char*)(&As[0][0]) + wave * 1024;
    char* lB = (char*)(&Bs[0][0]) + wave * 1024;

    f32x4 acc[4][4] = {};

    for (int k0 = 0; k0 < 512; k0 += 64) {
        __syncthreads();
        #pragma unroll
        for (int i = 0; i < 4; ++i) {
            gload16(gA + k0 + i * 16384, lA + i * 4096);
            gload16(gB + k0 + i * 16384, lB + i * 4096);
        }
        __syncthreads();
        #pragma unroll
        for (int kk = 0; kk < 64; kk += 32) {
            bf16x8 af[4], bg[4];
            #pragma unroll
            for (int x = 0; x < 4; ++x) {
                af[x] = *(const bf16x8*)&As[wr*64 + x*16 + llo][kk + lhi*8];
                bg[x] = *(const bf16x8*)&Bs[wc*64 + x*16 + llo][kk + lhi*8];
            }
            #pragma unroll
            for (int mi = 0; mi < 4; ++mi)
                #pragma unroll
                for (int ni = 0; ni < 4; ++ni)
                    acc[mi][ni] = MFMA_BF16(af[mi], bg[ni], acc[mi][ni], 0, 0, 0);
        }
    }

    float bn[4];
    #pragma unroll
    for (int ni = 0; ni < 4; ++ni) bn[ni] = bpr[nBase + wc*64 + ni*16 + llo];

    #pragma unroll
    for (int mi = 0; mi < 4; ++mi)
        #pragma unroll
        for (int ni = 0; ni < 4; ++ni)
            #pragma unroll
            for (int r = 0; r < 4; ++r)
                out[(size_t)(mBase + wr*64 + mi*16 + lhi*4 + r)*512
                    + nBase + wc*64 + ni*16 + llo] = acc[mi][ni][r] + bn[ni];
}

// ---------------------------------------------------------------------------
extern "C" void kernel_launch(void* const* d_in, const int* in_sizes, int n_in,
                              void* d_out, int out_size, void* d_ws, size_t ws_size,
                              hipStream_t stream) {
    const float* hs     = (const float*)d_in[0];
    const float* Wqkv   = (const float*)d_in[1];
    const float* bqkv   = (const float*)d_in[2];
    const float* Wproj  = (const float*)d_in[3];
    const float* bproj  = (const float*)d_in[4];
    const float* lsc    = (const float*)d_in[5];
    const float* cpb_w1 = (const float*)d_in[6];
    const float* cpb_b1 = (const float*)d_in[7];
    const float* cpb_w2 = (const float*)d_in[8];
    const float* coords = (const float*)d_in[9];
    const int*   relidx = (const int*)d_in[10];
    float* out = (float*)d_out;

    char* ws = (char*)d_ws;
    __bf16* qn     = (__bf16*)(ws);                 // 33554432 B
    __bf16* kn     = (__bf16*)(ws + 33554432);      // 33554432 B
    __bf16* vv     = (__bf16*)(ws + 67108864);      // 33554432 B
    __bf16* hsb    = (__bf16*)(ws + 100663296);     // 33554432 B (aliased w/ ctx)
    __bf16* ctx    = (__bf16*)(ws + 100663296);     // hsb dead after qkv_kernel
    float*  bt     = (float*)(ws + 134217728);      // 100800 B
    float*  bias_f = (float*)(ws + 134318528);      // 4194304 B
    __bf16* Wqb    = (__bf16*)(ws + 138512832);     // 1572864 B
    __bf16* Wpb    = (__bf16*)(ws + 140085696);     // 524288 B -> 140.6 MB total

    cvt_bf16_kernel<<<8192, 256, 0, stream>>>(hs, hsb);        // 128*256*512
    cvt_bf16_kernel<<<384, 256, 0, stream>>>(Wqkv, Wqb);       // 1536*512
    cvt_bf16_kernel<<<128, 256, 0, stream>>>(Wproj, Wpb);      // 512*512
    qkv_kernel<<<dim3(12, 256), 256, 0, stream>>>(hsb, Wqb, bqkv, lsc, qn, kn, vv);
    cpb_table_kernel<<<1575, 256, 0, stream>>>(cpb_w1, cpb_b1, cpb_w2, coords, bt);
    bias_gather_kernel<<<1024, 256, 0, stream>>>(bt, relidx, bias_f);
    attn_kernel<<<2048, 256, 0, stream>>>(qn, kn, vv, bias_f, ctx);
    proj_kernel<<<dim3(4, 256), 256, 0, stream>>>(ctx, Wpb, bproj, out);
}

// Round 7
// 317.722 us; speedup vs baseline: 1.9505x; 1.1423x over previous
//
#include <hip/hip_runtime.h>
#include <hip/hip_bf16.h>

typedef __bf16 bf16x8 __attribute__((ext_vector_type(8)));
typedef __bf16 bf16x4 __attribute__((ext_vector_type(4)));
typedef float  f32x4  __attribute__((ext_vector_type(4)));

#define MFMA_BF16 __builtin_amdgcn_mfma_f32_16x16x32_bf16

static __device__ __forceinline__ bf16x8 pack8(float4 a, float4 b) {
    bf16x8 r;
    r[0] = (__bf16)a.x; r[1] = (__bf16)a.y; r[2] = (__bf16)a.z; r[3] = (__bf16)a.w;
    r[4] = (__bf16)b.x; r[5] = (__bf16)b.y; r[6] = (__bf16)b.z; r[7] = (__bf16)b.w;
    return r;
}

static __device__ __forceinline__ void gload16(const void* g, void* l) {
    __builtin_amdgcn_global_load_lds(
        (const __attribute__((address_space(1))) unsigned int*)g,
        (__attribute__((address_space(3))) unsigned int*)l,
        16, 0, 0);
}

// ---------------------------------------------------------------------------
// Kernel 0: fp32 -> bf16 convert (8 elems/thread, exact grids)
// ---------------------------------------------------------------------------
__global__ __launch_bounds__(256) void cvt_bf16_kernel(
    const float* __restrict__ src, __bf16* __restrict__ dst)
{
    const size_t i = ((size_t)blockIdx.x * 256 + threadIdx.x) * 8;
    float4 a = *(const float4*)(src + i);
    float4 b = *(const float4*)(src + i + 4);
    *(bf16x8*)(dst + i) = pack8(a, b);
}

// ---------------------------------------------------------------------------
// Kernel 1: qkv GEMM, 128x128 tile, BK=64, global_load_lds staging.
// TRANSPOSED orientation: C-frag rows = feature n, cols = token m ->
// head-norm reduces over lhi (2 shfl_xor) and q/k store as one bf16x8 in a
// sigma-permuted d-layout (sigma identical for q,k => QK^T invariant; attn
// reads fragments at d=lhi*8 so no attn change). v stored natural.
// XCD-swizzled 1D grid: 3072 blocks (12 n-tiles x 256 m-tiles).
// ---------------------------------------------------------------------------
__global__ __launch_bounds__(256) void qkv_kernel(
    const __bf16* __restrict__ hsb, const __bf16* __restrict__ Wqb,
    const float* __restrict__ bqkv, const float* __restrict__ lsc,
    __bf16* __restrict__ qn, __bf16* __restrict__ kn, __bf16* __restrict__ vv)
{
    __shared__ __align__(16) __bf16 As[128][64];   // hs tile   (m rows)
    __shared__ __align__(16) __bf16 Bs[128][64];   // Wqkv tile (n rows)

    const int bid = blockIdx.x;                    // 3072, %8==0
    const int swz = (bid & 7) * 384 + (bid >> 3);  // XCD-contiguous work id
    const int tileM = swz / 12;
    const int tileN = swz - tileM * 12;
    const int nBase = tileN * 128;
    const int mBase = tileM * 128;

    const int t = threadIdx.x;
    const int wave = t >> 6, lane = t & 63;
    const int wr = wave >> 1, wc = wave & 1;       // wr: n-half, wc: m-half
    const int lhi = lane >> 4, llo = lane & 15;
    const int srow = t >> 3;
    const int scol = (t & 7) * 8;

    const __bf16* gA = hsb + (size_t)(mBase + srow) * 512 + scol;
    const __bf16* gB = Wqb + (size_t)(nBase + srow) * 512 + scol;
    char* lA = (char*)(&As[0][0]) + wave * 1024;
    char* lB = (char*)(&Bs[0][0]) + wave * 1024;

    f32x4 acc[4][4] = {};   // acc[i][j]: i = n-frag, j = m-frag

    for (int k0 = 0; k0 < 512; k0 += 64) {
        __syncthreads();
        #pragma unroll
        for (int i = 0; i < 4; ++i) {
            gload16(gA + k0 + i * 16384, lA + i * 4096);
            gload16(gB + k0 + i * 16384, lB + i * 4096);
        }
        __syncthreads();
        #pragma unroll
        for (int kk = 0; kk < 64; kk += 32) {
            bf16x8 af[4], bg[4];
            #pragma unroll
            for (int x = 0; x < 4; ++x) {
                af[x] = *(const bf16x8*)&Bs[wr*64 + x*16 + llo][kk + lhi*8];
                bg[x] = *(const bf16x8*)&As[wc*64 + x*16 + llo][kk + lhi*8];
            }
            #pragma unroll
            for (int i = 0; i < 4; ++i)
                #pragma unroll
                for (int j = 0; j < 4; ++j)
                    acc[i][j] = MFMA_BF16(af[i], bg[j], acc[i][j], 0, 0, 0);
        }
    }

    // D[n][m]: n = nW + i*16 + lhi*4 + r,  m = mBase + wc*64 + j*16 + llo
    const int nW = nBase + wr * 64;
    const int which = nW >> 9;          // 0=q 1=k 2=v (64-span never crosses)
    __bf16* outp = (which == 0) ? qn : (which == 1) ? kn : vv;

    float4 bq4[4];
    #pragma unroll
    for (int i = 0; i < 4; ++i)
        bq4[i] = *(const float4*)&bqkv[nW + i*16 + lhi*4];

    #pragma unroll
    for (int p = 0; p < 2; ++p) {       // frag pair (2p,2p+1) = one 32-d head
        const int h = ((nW + p*32) >> 5) & 15;
        const float sc = (which == 0) ? __expf(fminf(lsc[h], 4.6051701859880914f))
                                      : 1.0f;
        #pragma unroll
        for (int j = 0; j < 4; ++j) {
            float v0[4], v1[4];
            float ss = 0.f;
            #pragma unroll
            for (int r = 0; r < 4; ++r) {
                v0[r] = acc[2*p][j][r]   + ((const float*)&bq4[2*p])[r];
                v1[r] = acc[2*p+1][j][r] + ((const float*)&bq4[2*p+1])[r];
                ss += v0[r]*v0[r] + v1[r]*v1[r];
            }
            float f = 1.0f;
            if (which < 2) {
                ss += __shfl_xor(ss, 16);
                ss += __shfl_xor(ss, 32);
                f = sc / fmaxf(sqrtf(ss), 1e-12f);
            }
            const int m = mBase + wc*64 + j*16 + llo;
            const int b = m >> 8, s = m & 255;
            __bf16* dst = outp + ((size_t)(b*16 + h)*256 + s)*32;
            if (which < 2) {
                // sigma-permuted: lane's 8 values contiguous at lhi*8
                bf16x8 o;
                #pragma unroll
                for (int r = 0; r < 4; ++r) {
                    o[r]     = (__bf16)(v0[r] * f);
                    o[r + 4] = (__bf16)(v1[r] * f);
                }
                *(bf16x8*)(dst + lhi*8) = o;
            } else {
                // v: natural d layout (PV output d must be real)
                bf16x4 oa, ob;
                #pragma unroll
                for (int r = 0; r < 4; ++r) {
                    oa[r] = (__bf16)v0[r];
                    ob[r] = (__bf16)v1[r];
                }
                *(bf16x4*)(dst + lhi*4)      = oa;
                *(bf16x4*)(dst + 16 + lhi*4) = ob;
            }
        }
    }
}

// ---------------------------------------------------------------------------
// Kernel 2a: bias_table[e][h] = (relu(coords[e] @ w1^T + b1)) @ w2^T
// ---------------------------------------------------------------------------
__global__ __launch_bounds__(256) void cpb_table_kernel(
    const float* __restrict__ w1, const float* __restrict__ b1,
    const float* __restrict__ w2, const float* __restrict__ coords,
    float* __restrict__ bias_table)
{
    __shared__ float hid[512];
    __shared__ float part[16][17];
    const int e = blockIdx.x;
    const float x = coords[e*3+0], y = coords[e*3+1], z = coords[e*3+2];
    const int t = threadIdx.x;
    for (int c = t; c < 512; c += 256) {
        float v = w1[c*3+0]*x + w1[c*3+1]*y + w1[c*3+2]*z + b1[c];
        hid[c] = fmaxf(v, 0.f);
    }
    __syncthreads();
    const int hh = t >> 4, seg = t & 15;
    float p = 0.f;
    #pragma unroll
    for (int j = 0; j < 32; ++j) p += w2[hh*512 + seg*32 + j] * hid[seg*32 + j];
    part[hh][seg] = p;
    __syncthreads();
    if (t < 16) {
        float s = 0.f;
        #pragma unroll
        for (int i = 0; i < 16; ++i) s += part[t][i];
        bias_table[e*16 + t] = s;
    }
}

// ---------------------------------------------------------------------------
// Kernel 2b: bias in TRANSPOSED MFMA C-fragment layout (for swapped QK^T):
// lane reg r holds (q = i16*16 + (lane&15), k = j16*16 + (lane>>4)*4 + r),
// with -26 folded in so exp(s) <= 1.
// ---------------------------------------------------------------------------
__global__ __launch_bounds__(256) void bias_gather_kernel(
    const float* __restrict__ bias_table, const int* __restrict__ rel_index,
    float* __restrict__ bias_f)
{
    const int tid = blockIdx.x * 256 + threadIdx.x;   // 262144 total
    const int lane = tid & 63;
    const int j16 = (tid >> 6) & 15;
    const int i16 = (tid >> 10) & 15;
    const int h   = tid >> 14;
    const int llo = lane & 15, lhi = lane >> 4;
    const int qrow = i16*16 + llo;
    float4 o;
    #pragma unroll
    for (int r = 0; r < 4; ++r) {
        int kcol = j16*16 + lhi*4 + r;
        int idx = rel_index[qrow*256 + kcol];
        float v = bias_table[idx*16 + h];
        (&o.x)[r] = 16.f / (1.f + __expf(-v)) - 26.0f;
    }
    ((float4*)bias_f)[tid] = o;
}

// ---------------------------------------------------------------------------
// Kernel 3: attention per (b,h). Swapped QK^T (r4-proven, unchanged —
// q/k sigma-permutation is transparent: fragments read at d=lhi*8).
// ---------------------------------------------------------------------------
__global__ __launch_bounds__(256) void attn_kernel(
    const __bf16* __restrict__ qn, const __bf16* __restrict__ kn,
    const __bf16* __restrict__ vv, const float* __restrict__ bias_f,
    __bf16* __restrict__ ctx)
{
    __shared__ __align__(16) __bf16 Kl[256][40];    // 20480 B
    __shared__ __align__(16) __bf16 Vt[32][264];    // 16896 B

    const int bh = blockIdx.x;
    const int b = bh >> 4, h = bh & 15;
    const int t = threadIdx.x;
    const int wave = t >> 6, lane = t & 63;
    const int lhi = lane >> 4, llo = lane & 15;
    const size_t base = (size_t)bh * 8192;

    {
        const __bf16* sk = kn + base + t*32;
        #pragma unroll
        for (int j = 0; j < 4; ++j)
            *(bf16x8*)&Kl[t][j*8] = *(const bf16x8*)(sk + j*8);

        const int u = t & 31;
        const int slot = (t & ~31) + 8*((u & 15) >> 2) + (u & 3) + ((u >> 4) & 1)*4;
        const __bf16* sv = vv + base + t*32;
        #pragma unroll
        for (int j = 0; j < 4; ++j) {
            bf16x8 v8 = *(const bf16x8*)(sv + j*8);
            #pragma unroll
            for (int e = 0; e < 8; ++e) Vt[j*8 + e][slot] = v8[e];
        }
    }
    __syncthreads();

    const f32x4* bp4 = (const f32x4*)bias_f + (size_t)h * 16384;

    #pragma unroll 1
    for (int qt = 0; qt < 4; ++qt) {
        const int i16 = wave*4 + qt;
        const int row0 = i16*16;
        bf16x8 bq = *(const bf16x8*)(qn + base + (size_t)(row0 + llo)*32 + lhi*8);

        f32x4 o0 = {0.f,0.f,0.f,0.f}, o1 = {0.f,0.f,0.f,0.f};
        float sum = 0.f;

        #pragma unroll 2
        for (int c = 0; c < 8; ++c) {
            f32x4 bfA = bp4[((size_t)i16*16 + 2*c    )*64 + lane];
            f32x4 bfB = bp4[((size_t)i16*16 + 2*c + 1)*64 + lane];

            bf16x8 ka0 = *(const bf16x8*)&Kl[c*32 + llo][lhi*8];
            bf16x8 ka1 = *(const bf16x8*)&Kl[c*32 + 16 + llo][lhi*8];

            __builtin_amdgcn_s_setprio(1);
            f32x4 stA = MFMA_BF16(ka0, bq, bfA, 0, 0, 0);
            f32x4 stB = MFMA_BF16(ka1, bq, bfB, 0, 0, 0);
            __builtin_amdgcn_s_setprio(0);

            bf16x8 pa;
            #pragma unroll
            for (int r = 0; r < 4; ++r) {
                float eA = __expf(stA[r]);
                float eB = __expf(stB[r]);
                sum += eA + eB;
                pa[r]     = (__bf16)eA;
                pa[r + 4] = (__bf16)eB;
            }

            bf16x8 bv0 = *(const bf16x8*)&Vt[llo][c*32 + lhi*8];
            bf16x8 bv1 = *(const bf16x8*)&Vt[16 + llo][c*32 + lhi*8];

            __builtin_amdgcn_s_setprio(1);
            o0 = MFMA_BF16(pa, bv0, o0, 0, 0, 0);
            o1 = MFMA_BF16(pa, bv1, o1, 0, 0, 0);
            __builtin_amdgcn_s_setprio(0);
        }

        sum += __shfl_xor(sum, 16);
        sum += __shfl_xor(sum, 32);

        #pragma unroll
        for (int r = 0; r < 4; ++r) {
            float inv = __builtin_amdgcn_rcpf(__shfl(sum, lhi*4 + r));
            int srow = row0 + lhi*4 + r;
            __bf16* cp = ctx + ((size_t)(b*256 + srow))*512 + h*32;
            cp[llo]      = (__bf16)(o0[r] * inv);
            cp[16 + llo] = (__bf16)(o1[r] * inv);
        }
    }
}

// ---------------------------------------------------------------------------
// Kernel 4: out = ctx @ Wproj^T + bproj, 128x128 tile, XCD-swizzled 1D grid
// (1024 blocks = 4 n-tiles x 256 m-tiles).
// ---------------------------------------------------------------------------
__global__ __launch_bounds__(256) void proj_kernel(
    const __bf16* __restrict__ ctx, const __bf16* __restrict__ Wpb,
    const float* __restrict__ bpr, float* __restrict__ out)
{
    __shared__ __align__(16) __bf16 As[128][64];
    __shared__ __align__(16) __bf16 Bs[128][64];

    const int bid = blockIdx.x;                    // 1024, %8==0
    const int swz = (bid & 7) * 128 + (bid >> 3);
    const int nBase = (swz & 3) * 128;
    const int mBase = (swz >> 2) * 128;

    const int t = threadIdx.x;
    const int wave = t >> 6, lane = t & 63;
    const int wr = wave >> 1, wc = wave & 1;
    const int lhi = lane >> 4, llo = lane & 15;
    const int srow = t >> 3;
    const int scol = (t & 7) * 8;

    const __bf16* gA = ctx + (size_t)(mBase + srow) * 512 + scol;
    const __bf16* gB = Wpb + (size_t)(nBase + srow) * 512 + scol;
    char* lA = (char*)(&As[0][0]) + wave * 1024;
    char* lB = (char*)(&Bs[0][0]) + wave * 1024;

    f32x4 acc[4][4] = {};

    for (int k0 = 0; k0 < 512; k0 += 64) {
        __syncthreads();
        #pragma unroll
        for (int i = 0; i < 4; ++i) {
            gload16(gA + k0 + i * 16384, lA + i * 4096);
            gload16(gB + k0 + i * 16384, lB + i * 4096);
        }
        __syncthreads();
        #pragma unroll
        for (int kk = 0; kk < 64; kk += 32) {
            bf16x8 af[4], bg[4];
            #pragma unroll
            for (int x = 0; x < 4; ++x) {
                af[x] = *(const bf16x8*)&As[wr*64 + x*16 + llo][kk + lhi*8];
                bg[x] = *(const bf16x8*)&Bs[wc*64 + x*16 + llo][kk + lhi*8];
            }
            #pragma unroll
            for (int mi = 0; mi < 4; ++mi)
                #pragma unroll
                for (int ni = 0; ni < 4; ++ni)
                    acc[mi][ni] = MFMA_BF16(af[mi], bg[ni], acc[mi][ni], 0, 0, 0);
        }
    }

    float bn[4];
    #pragma unroll
    for (int ni = 0; ni < 4; ++ni) bn[ni] = bpr[nBase + wc*64 + ni*16 + llo];

    #pragma unroll
    for (int mi = 0; mi < 4; ++mi)
        #pragma unroll
        for (int ni = 0; ni < 4; ++ni)
            #pragma unroll
            for (int r = 0; r < 4; ++r)
                out[(size_t)(mBase + wr*64 + mi*16 + lhi*4 + r)*512
                    + nBase + wc*64 + ni*16 + llo] = acc[mi][ni][r] + bn[ni];
}

// ---------------------------------------------------------------------------
extern "C" void kernel_launch(void* const* d_in, const int* in_sizes, int n_in,
                              void* d_out, int out_size, void* d_ws, size_t ws_size,
                              hipStream_t stream) {
    const float* hs     = (const float*)d_in[0];
    const float* Wqkv   = (const float*)d_in[1];
    const float* bqkv   = (const float*)d_in[2];
    const float* Wproj  = (const float*)d_in[3];
    const float* bproj  = (const float*)d_in[4];
    const float* lsc    = (const float*)d_in[5];
    const float* cpb_w1 = (const float*)d_in[6];
    const float* cpb_b1 = (const float*)d_in[7];
    const float* cpb_w2 = (const float*)d_in[8];
    const float* coords = (const float*)d_in[9];
    const int*   relidx = (const int*)d_in[10];
    float* out = (float*)d_out;

    char* ws = (char*)d_ws;
    __bf16* qn     = (__bf16*)(ws);                 // 33554432 B
    __bf16* kn     = (__bf16*)(ws + 33554432);      // 33554432 B
    __bf16* vv     = (__bf16*)(ws + 67108864);      // 33554432 B
    __bf16* hsb    = (__bf16*)(ws + 100663296);     // 33554432 B (aliased w/ ctx)
    __bf16* ctx    = (__bf16*)(ws + 100663296);     // hsb dead after qkv_kernel
    float*  bt     = (float*)(ws + 134217728);      // 100800 B
    float*  bias_f = (float*)(ws + 134318528);      // 4194304 B
    __bf16* Wqb    = (__bf16*)(ws + 138512832);     // 1572864 B
    __bf16* Wpb    = (__bf16*)(ws + 140085696);     // 524288 B -> 140.6 MB total

    cvt_bf16_kernel<<<8192, 256, 0, stream>>>(hs, hsb);        // 128*256*512
    cvt_bf16_kernel<<<384, 256, 0, stream>>>(Wqkv, Wqb);       // 1536*512
    cvt_bf16_kernel<<<128, 256, 0, stream>>>(Wproj, Wpb);      // 512*512
    qkv_kernel<<<3072, 256, 0, stream>>>(hsb, Wqb, bqkv, lsc, qn, kn, vv);
    cpb_table_kernel<<<1575, 256, 0, stream>>>(cpb_w1, cpb_b1, cpb_w2, coords, bt);
    bias_gather_kernel<<<1024, 256, 0, stream>>>(bt, relidx, bias_f);
    attn_kernel<<<2048, 256, 0, stream>>>(qn, kn, vv, bias_f, ctx);
    proj_kernel<<<1024, 256, 0, stream>>>(ctx, Wpb, bproj, out);
}